// Round 1
// baseline (590.468 us; speedup 1.0000x reference)
//
#include <hip/hip_runtime.h>
#include <hip/hip_bf16.h>

#define BATCH 2048
#define IN_DIM 128
#define GRIDN 128
#define HID 256
#define DEPTH 7

typedef unsigned int u32;
typedef __attribute__((ext_vector_type(8))) short short8;
typedef __attribute__((ext_vector_type(4))) float floatx4;

// ---------------- ws layout (bytes) ----------------
#define OFF_FST   ((size_t)0)                     // bf16 fs_t [7][128][256][128]
#define SZ_FST    ((size_t)7*128*256*128*2)       // 58,720,256
#define OFF_Z     (OFF_FST + SZ_FST)              // fp32 z [2048][128]
#define SZ_Z      ((size_t)BATCH*IN_DIM*4)
#define OFF_HPRE  (OFF_Z + SZ_Z)                  // fp32 h_pre [2048][256]
#define SZ_HPRE   ((size_t)BATCH*HID*4)
#define OFF_STATS (OFF_HPRE + SZ_HPRE)            // fp32 stats 3*[512]
#define SZ_STATS  ((size_t)3*2*HID*4)
#define OFF_CW    (OFF_STATS + SZ_STATS)          // fp32 cw[7] (+pad)
#define SZ_CW     ((size_t)32)
#define OFF_Y1    (OFF_CW + SZ_CW)
#define SZ_Y      ((size_t)BATCH*HID*4)
#define OFF_Y2    (OFF_Y1 + SZ_Y)
#define OFF_Y3    (OFF_Y2 + SZ_Y)

__device__ __forceinline__ void gload_lds16(const void* g, void* l) {
  __builtin_amdgcn_global_load_lds(
      (const __attribute__((address_space(1))) u32*)g,
      (__attribute__((address_space(3))) u32*)l, 16, 0, 0);
}

__device__ __forceinline__ u32 pack2_bf16(float lo, float hi) {
  __hip_bfloat162 b2;
  b2.x = __float2bfloat16(lo);
  b2.y = __float2bfloat16(hi);
  return *reinterpret_cast<u32*>(&b2);
}

__device__ __forceinline__ float gelu_exact(float x) {
  return 0.5f * x * (1.0f + erff(x * 0.70710678118654752f));
}

// ---------------- prep: min/max -> z, softmax cumweights ----------------
__global__ void prep_kernel(const float* __restrict__ x,
                            const float* __restrict__ depth_scores,
                            float* __restrict__ z, float* __restrict__ cw) {
  int i = blockIdx.x;   // feature
  int t = threadIdx.x;  // 256 threads
  __shared__ float smn[256], smx[256];
  float v[8];
  float mn = 1e30f, mx = -1e30f;
#pragma unroll
  for (int j = 0; j < 8; ++j) {
    int b = t + j * 256;
    v[j] = x[(size_t)b * IN_DIM + i];
    mn = fminf(mn, v[j]); mx = fmaxf(mx, v[j]);
  }
  smn[t] = mn; smx[t] = mx;
  __syncthreads();
  for (int s = 128; s > 0; s >>= 1) {
    if (t < s) { smn[t] = fminf(smn[t], smn[t+s]); smx[t] = fmaxf(smx[t], smx[t+s]); }
    __syncthreads();
  }
  float lo = smn[0];
  float inv = 1.0f / (smx[0] - lo + 1e-6f);
#pragma unroll
  for (int j = 0; j < 8; ++j) {
    int b = t + j * 256;
    z[(size_t)b * IN_DIM + i] = (v[j] - lo) * inv;
  }
  if (i == 0 && t == 0) {
    float m = -1e30f;
    for (int d0 = 0; d0 < DEPTH; ++d0) m = fmaxf(m, depth_scores[d0]);
    float e[DEPTH]; float sum = 0.f;
    for (int d0 = 0; d0 < DEPTH; ++d0) { e[d0] = expf(depth_scores[d0] - m); sum += e[d0]; }
    float cacc = 0.f;
    float cs[DEPTH];
    for (int d0 = DEPTH - 1; d0 >= 0; --d0) { cacc += e[d0] / sum; cs[d0] = cacc; }
    for (int d0 = 0; d0 < DEPTH; ++d0) cw[d0] = cs[d0];
  }
}

// ---------------- fs fp32 [d,i,g,h] -> bf16 transposed [d,i,h,g] ----------------
__global__ void convert_kernel(const float* __restrict__ fs,
                               __hip_bfloat16* __restrict__ fs_t) {
  int blk = blockIdx.x;              // d*128 + i
  int t = threadIdx.x;
  int w = t >> 6, l = t & 63;
  int h = w * 64 + l;
  const float* src = fs + (size_t)blk * (GRIDN * HID) + h;          // stride HID over g
  __hip_bfloat16* dst = fs_t + (size_t)blk * (HID * GRIDN) + (size_t)h * GRIDN;
#pragma unroll
  for (int c = 0; c < 4; ++c) {
    int g0 = c * 32;
    float vv[32];
#pragma unroll
    for (int g = 0; g < 32; ++g) vv[g] = src[(size_t)(g0 + g) * HID];
    u32 out[16];
#pragma unroll
    for (int p = 0; p < 16; ++p) out[p] = pack2_bf16(vv[2*p], vv[2*p+1]);
    uint4* d4 = reinterpret_cast<uint4*>(dst + g0);
#pragma unroll
    for (int q = 0; q < 4; ++q)
      d4[q] = make_uint4(out[4*q], out[4*q+1], out[4*q+2], out[4*q+3]);
  }
}

// ---------------- big GEMM: h_pre += c_d * relu(z-grids) @ fs ----------------
// grid: 8 mtiles x 28 (7 depth x 4 i-chunks) = 224 blocks, 512 threads (8 waves)
// LDS: A slots [16 u][2 s][64 lanes][16B] = 32KB, B slots [16 t][2 s][64][16B] = 32KB
__launch_bounds__(512, 2)
__global__ void gemm_kernel(const float* __restrict__ z,
                            const float* __restrict__ grids,
                            const __hip_bfloat16* __restrict__ fs_t,
                            const float* __restrict__ cw,
                            float* __restrict__ h_pre) {
  __shared__ __align__(16) char lds[65536];
  char* ldsA = lds;
  char* ldsB = lds + 32768;

  int bx = blockIdx.x;
  int mtile = bx & 7;
  int chunk = bx >> 3;        // 0..27
  int d = chunk >> 2;
  int ibase = (chunk & 3) * 32;

  int tid = threadIdx.x;
  int w = tid >> 6, l = tid & 63;
  int l15 = l & 15, l4 = l >> 4;
  int wm = w >> 2;            // 0..1 m-half (128 rows)
  int wn = w & 3;             // 0..3 n-quarter (64 cols)

  floatx4 acc[8][4];
#pragma unroll
  for (int a = 0; a < 8; ++a)
#pragma unroll
    for (int b = 0; b < 4; ++b) acc[a][b] = (floatx4)0.f;

  int mrow0 = mtile * 256 + 16 * (w * 2 + 0) + l15;
  int mrow1 = mtile * 256 + 16 * (w * 2 + 1) + l15;

  const __hip_bfloat16* fsd = fs_t + (size_t)d * 128 * (HID * GRIDN);

  for (int it = 0; it < 64; ++it) {
    int i = ibase + (it >> 1);
    int kh = it & 1;

    float zv0 = z[(size_t)mrow0 * IN_DIM + i];
    float zv1 = z[(size_t)mrow1 * IN_DIM + i];
    const float* gp = grids + ((size_t)d * IN_DIM + i) * GRIDN + kh * 64 + l4 * 8;
    float4 ga0 = *(const float4*)(gp);
    float4 ga1 = *(const float4*)(gp + 4);
    float4 gb0 = *(const float4*)(gp + 32);
    float4 gb1 = *(const float4*)(gp + 36);

    __syncthreads();  // previous compute done reading LDS

    // async B staging: this wave fills slots t = w*2, w*2+1 (s = 0,1)
    const __hip_bfloat16* fsslab = fsd + (size_t)i * (HID * GRIDN);
#pragma unroll
    for (int j2 = 0; j2 < 4; ++j2) {
      int t2 = w * 2 + (j2 >> 1);
      int s2 = j2 & 1;
      const __hip_bfloat16* g =
          fsslab + (size_t)(16 * t2 + l15) * GRIDN + kh * 64 + s2 * 32 + l4 * 8;
      gload_lds16(g, ldsB + (t2 * 2 + s2) * 1024);
    }

    // A generation: relu(z - grid), bf16, fragment-native layout
#pragma unroll
    for (int j = 0; j < 2; ++j) {
      float zv = j ? zv1 : zv0;
#pragma unroll
      for (int s = 0; s < 2; ++s) {
        float4 gA = s ? gb0 : ga0;
        float4 gB = s ? gb1 : ga1;
        float a0 = fmaxf(zv - gA.x, 0.f), a1 = fmaxf(zv - gA.y, 0.f);
        float a2 = fmaxf(zv - gA.z, 0.f), a3 = fmaxf(zv - gA.w, 0.f);
        float a4 = fmaxf(zv - gB.x, 0.f), a5 = fmaxf(zv - gB.y, 0.f);
        float a6 = fmaxf(zv - gB.z, 0.f), a7 = fmaxf(zv - gB.w, 0.f);
        uint4 pk;
        pk.x = pack2_bf16(a0, a1); pk.y = pack2_bf16(a2, a3);
        pk.z = pack2_bf16(a4, a5); pk.w = pack2_bf16(a6, a7);
        *(uint4*)(ldsA + ((((w * 2 + j) * 2 + s) * 64 + l) * 16)) = pk;
      }
    }
    __syncthreads();  // staging (incl. async loads) visible

    // compute: 2 ksteps x (8 A-frags x 4 B-frags) MFMAs
#pragma unroll
    for (int s = 0; s < 2; ++s) {
      short8 af[8], bf[4];
#pragma unroll
      for (int uu = 0; uu < 8; ++uu)
        af[uu] = *(const short8*)(ldsA + ((((wm * 8 + uu) * 2 + s) * 64 + l) * 16));
#pragma unroll
      for (int tt = 0; tt < 4; ++tt)
        bf[tt] = *(const short8*)(ldsB + ((((wn * 4 + tt) * 2 + s) * 64 + l) * 16));
#pragma unroll
      for (int uu = 0; uu < 8; ++uu)
#pragma unroll
        for (int tt = 0; tt < 4; ++tt)
          acc[uu][tt] = __builtin_amdgcn_mfma_f32_16x16x32_bf16(af[uu], bf[tt], acc[uu][tt], 0, 0, 0);
    }
  }

  // epilogue: scale by c_d, atomic accumulate
  float cd = cw[d];
  int row0 = mtile * 256 + wm * 128 + l4 * 4;
  int col0 = wn * 64 + l15;
#pragma unroll
  for (int uu = 0; uu < 8; ++uu) {
#pragma unroll
    for (int tt = 0; tt < 4; ++tt) {
      int col = col0 + tt * 16;
#pragma unroll
      for (int r = 0; r < 4; ++r) {
        int row = row0 + uu * 16 + r;
        atomicAdd(&h_pre[(size_t)row * HID + col], cd * acc[uu][tt][r]);
      }
    }
  }
}

// ---------------- MLP layer: Y = act(X) @ W + b, col stats of Y ----------------
template <int FIRST>
__global__ void mlp_kernel(const float* __restrict__ Xin,
                           const float* __restrict__ statsIn,
                           const float* __restrict__ gamma,
                           const float* __restrict__ beta,
                           const float* __restrict__ W,
                           const float* __restrict__ bias,
                           float* __restrict__ Yout,
                           float* __restrict__ statsOut) {
  __shared__ float Xs[8][HID];
  int br = blockIdx.x, c = threadIdx.x;
  float mean = 0.f, rstd = 1.f, gm = 1.f, bt = 0.f;
  if (!FIRST) {
    float s1 = statsIn[c], s2 = statsIn[HID + c];
    mean = s1 * (1.0f / BATCH);
    float var = s2 * (1.0f / BATCH) - mean * mean;
    rstd = rsqrtf(var + 1e-5f);
    gm = gamma[c]; bt = beta[c];
  }
#pragma unroll
  for (int r = 0; r < 8; ++r) {
    float v = Xin[(size_t)(br * 8 + r) * HID + c];
    if (!FIRST) v = gelu_exact((v - mean) * rstd * gm + bt);
    Xs[r][c] = v;
  }
  __syncthreads();
  float acc[8] = {0, 0, 0, 0, 0, 0, 0, 0};
  for (int k = 0; k < HID; ++k) {
    float wv = W[(size_t)k * HID + c];
#pragma unroll
    for (int r = 0; r < 8; ++r) acc[r] += Xs[r][k] * wv;
  }
  float bb = bias[c];
  float s1 = 0.f, s2 = 0.f;
#pragma unroll
  for (int r = 0; r < 8; ++r) {
    float y = acc[r] + bb;
    Yout[(size_t)(br * 8 + r) * HID + c] = y;
    s1 += y; s2 += y * y;
  }
  atomicAdd(&statsOut[c], s1);
  atomicAdd(&statsOut[HID + c], s2);
}

// ---------------- final: out = gelu(bn(Y3)) @ W_out + b_out ----------------
__global__ void final_kernel(const float* __restrict__ Y3,
                             const float* __restrict__ statsIn,
                             const float* __restrict__ gamma,
                             const float* __restrict__ beta,
                             const float* __restrict__ W_out,
                             const float* __restrict__ b_out,
                             float* __restrict__ out) {
  int w = threadIdx.x >> 6, l = threadIdx.x & 63;
  int b = blockIdx.x * 4 + w;
  float4 y = *(const float4*)(Y3 + (size_t)b * HID + l * 4);
  float4 wv = *(const float4*)(W_out + l * 4);
  float r4[4] = {y.x, y.y, y.z, y.w};
  float w4[4] = {wv.x, wv.y, wv.z, wv.w};
  float s = 0.f;
  int c0 = l * 4;
#pragma unroll
  for (int q = 0; q < 4; ++q) {
    int c = c0 + q;
    float s1 = statsIn[c], s2 = statsIn[HID + c];
    float mean = s1 * (1.0f / BATCH);
    float var = s2 * (1.0f / BATCH) - mean * mean;
    float rstd = rsqrtf(var + 1e-5f);
    float v = gelu_exact((r4[q] - mean) * rstd * gamma[c] + beta[c]);
    s += v * w4[q];
  }
#pragma unroll
  for (int off = 32; off > 0; off >>= 1) s += __shfl_down(s, off);
  if (l == 0) out[b] = s + b_out[0];
}

extern "C" void kernel_launch(void* const* d_in, const int* in_sizes, int n_in,
                              void* d_out, int out_size, void* d_ws, size_t ws_size,
                              hipStream_t stream) {
  const float* x      = (const float*)d_in[0];
  const float* grids  = (const float*)d_in[1];
  const float* fs     = (const float*)d_in[2];
  const float* dscore = (const float*)d_in[3];
  const float* mlp_W  = (const float*)d_in[4];
  const float* mlp_b  = (const float*)d_in[5];
  const float* bn_g   = (const float*)d_in[6];
  const float* bn_b   = (const float*)d_in[7];
  const float* W_out  = (const float*)d_in[8];
  const float* b_out  = (const float*)d_in[9];
  float* out = (float*)d_out;

  char* ws = (char*)d_ws;
  __hip_bfloat16* fs_t = (__hip_bfloat16*)(ws + OFF_FST);
  float* z     = (float*)(ws + OFF_Z);
  float* h_pre = (float*)(ws + OFF_HPRE);
  float* stats = (float*)(ws + OFF_STATS);
  float* cw    = (float*)(ws + OFF_CW);
  float* Y1    = (float*)(ws + OFF_Y1);
  float* Y2    = (float*)(ws + OFF_Y2);
  float* Y3    = (float*)(ws + OFF_Y3);

  // zero the atomic accumulators (h_pre + all BN stats)
  hipMemsetAsync(h_pre, 0, SZ_HPRE + SZ_STATS, stream);

  prep_kernel<<<128, 256, 0, stream>>>(x, dscore, z, cw);
  convert_kernel<<<DEPTH * IN_DIM, 256, 0, stream>>>(fs, fs_t);
  gemm_kernel<<<8 * DEPTH * 4, 512, 0, stream>>>(z, grids, fs_t, cw, h_pre);

  mlp_kernel<1><<<256, 256, 0, stream>>>(h_pre, nullptr, nullptr, nullptr,
                                         mlp_W, mlp_b, Y1, stats);
  mlp_kernel<0><<<256, 256, 0, stream>>>(Y1, stats, bn_g, bn_b,
                                         mlp_W + 65536, mlp_b + 256, Y2, stats + 512);
  mlp_kernel<0><<<256, 256, 0, stream>>>(Y2, stats + 512, bn_g + 256, bn_b + 256,
                                         mlp_W + 2 * 65536, mlp_b + 2 * 256, Y3, stats + 1024);
  final_kernel<<<512, 256, 0, stream>>>(Y3, stats + 1024, bn_g + 512, bn_b + 512,
                                        W_out, b_out, out);
}

// Round 2
// 536.239 us; speedup vs baseline: 1.1011x; 1.1011x over previous
//
#include <hip/hip_runtime.h>
#include <hip/hip_bf16.h>

#define BATCH 2048
#define IN_DIM 128
#define GRIDN 128
#define HID 256
#define DEPTH 7

typedef unsigned int u32;
typedef __attribute__((ext_vector_type(8))) short short8;
typedef __attribute__((ext_vector_type(4))) float floatx4;

// ---------------- ws layout (bytes) ----------------
#define OFF_FST   ((size_t)0)                     // bf16 fs_t [7][128][256][128]
#define SZ_FST    ((size_t)7*128*256*128*2)       // 58,720,256
#define OFF_Z     (OFF_FST + SZ_FST)              // fp32 z [2048][128]
#define SZ_Z      ((size_t)BATCH*IN_DIM*4)
#define OFF_HPRE  (OFF_Z + SZ_Z)                  // fp32 h_pre [2048][256]
#define SZ_HPRE   ((size_t)BATCH*HID*4)
#define OFF_STATS (OFF_HPRE + SZ_HPRE)            // fp32 stats 3*[512]
#define SZ_STATS  ((size_t)3*2*HID*4)
#define OFF_KEYS  (OFF_STATS + SZ_STATS)          // u32 keys [256]
#define SZ_KEYS   ((size_t)256*4)
#define OFF_CW    (OFF_KEYS + SZ_KEYS)            // fp32 cw[7] (+pad)
#define SZ_CW     ((size_t)32)
#define OFF_Y1    (OFF_CW + SZ_CW)
#define SZ_Y      ((size_t)BATCH*HID*4)
#define OFF_Y2    (OFF_Y1 + SZ_Y)
#define OFF_Y3    (OFF_Y2 + SZ_Y)

__device__ __forceinline__ void gload_lds16(const void* g, void* l) {
  __builtin_amdgcn_global_load_lds(
      (const __attribute__((address_space(1))) u32*)g,
      (__attribute__((address_space(3))) u32*)l, 16, 0, 0);
}

__device__ __forceinline__ u32 pack2_bf16(float lo, float hi) {
  __hip_bfloat162 b2;
  b2.x = __float2bfloat16(lo);
  b2.y = __float2bfloat16(hi);
  return *reinterpret_cast<u32*>(&b2);
}

__device__ __forceinline__ float gelu_exact(float x) {
  return 0.5f * x * (1.0f + erff(x * 0.70710678118654752f));
}

// ---------------- prep1: coalesced per-feature min/max via monotone-key atomics
// x in [0,1): float bits are monotone; minkey = 0x7FFFFFFF - bits (atomicMax, init 0)
__global__ void prep1_kernel(const float* __restrict__ x, u32* __restrict__ keys) {
  int t = threadIdx.x;
  int base = blockIdx.x * 256 + t;
  float mn = 1e30f, mx = -1e30f;
#pragma unroll
  for (int j = 0; j < 16; ++j) {
    float v = x[base + j * 16384];   // 16384 % 128 == 0 -> same feature i each iter
    mn = fminf(mn, v); mx = fmaxf(mx, v);
  }
  __shared__ float smn[256], smx[256];
  smn[t] = mn; smx[t] = mx;
  __syncthreads();
  if (t < 128) {
    mn = fminf(smn[t], smn[t + 128]);
    mx = fmaxf(smx[t], smx[t + 128]);
    int i = base & 127;  // == t
    atomicMax(&keys[i], 0x7FFFFFFFu - __float_as_uint(mn));
    atomicMax(&keys[128 + i], __float_as_uint(mx));
  }
}

// ---------------- prep2: z = (x-mn)/(mx-mn+1e-6) coalesced; cw on block 0
__global__ void prep2_kernel(const float* __restrict__ x, const u32* __restrict__ keys,
                             const float* __restrict__ depth_scores,
                             float* __restrict__ z, float* __restrict__ cw) {
  int t = threadIdx.x;
#pragma unroll
  for (int j = 0; j < 4; ++j) {
    int f = blockIdx.x * 1024 + j * 256 + t;
    int i = f & 127;
    float mnv = __uint_as_float(0x7FFFFFFFu - keys[i]);
    float mxv = __uint_as_float(keys[128 + i]);
    z[f] = (x[f] - mnv) * (1.0f / (mxv - mnv + 1e-6f));
  }
  if (blockIdx.x == 0 && t == 0) {
    float m = -1e30f;
    for (int d0 = 0; d0 < DEPTH; ++d0) m = fmaxf(m, depth_scores[d0]);
    float e[DEPTH]; float sum = 0.f;
    for (int d0 = 0; d0 < DEPTH; ++d0) { e[d0] = expf(depth_scores[d0] - m); sum += e[d0]; }
    float cacc = 0.f; float cs[DEPTH];
    for (int d0 = DEPTH - 1; d0 >= 0; --d0) { cacc += e[d0] / sum; cs[d0] = cacc; }
    for (int d0 = 0; d0 < DEPTH; ++d0) cw[d0] = cs[d0];
  }
}

// ---------------- fs fp32 [d,i,g,h] -> bf16 transposed [d,i,h,g], via LDS ----------------
// block = one (d,i) slab; coalesced loads AND coalesced full-line stores.
__global__ void convert_kernel(const float* __restrict__ fs,
                               __hip_bfloat16* __restrict__ fs_t) {
  __shared__ u32 lds[256 * 33];   // [h][33] u32 rows: +1 pad -> conflict-free
  int slab = blockIdx.x;          // d*128 + i
  int t = threadIdx.x;
  const float* src = fs + (size_t)slab * (GRIDN * HID);
  char* dstb = (char*)(fs_t + (size_t)slab * (HID * GRIDN));

  for (int gh = 0; gh < 2; ++gh) {
    // phase 1: thread t owns row h=t; read 64 g coalesced (lanes over h)
    const float* s0 = src + (size_t)gh * 64 * HID + t;
#pragma unroll
    for (int g2 = 0; g2 < 32; ++g2) {
      float va = s0[(size_t)(2 * g2) * HID];
      float vb = s0[(size_t)(2 * g2 + 1) * HID];
      lds[t * 33 + g2] = pack2_bf16(va, vb);
    }
    __syncthreads();
    // phase 2: 8 tasks/thread, each stores 16B (full-cacheline coverage)
#pragma unroll
    for (int it2 = 0; it2 < 8; ++it2) {
      int task = t + it2 * 256;      // [0,2048)
      int h = task >> 3, m = task & 7;
      u32 a0 = lds[h * 33 + m * 4 + 0];
      u32 a1 = lds[h * 33 + m * 4 + 1];
      u32 a2 = lds[h * 33 + m * 4 + 2];
      u32 a3 = lds[h * 33 + m * 4 + 3];
      *(uint4*)(dstb + (size_t)h * 256 + gh * 128 + m * 16) = make_uint4(a0, a1, a2, a3);
    }
    __syncthreads();
  }
}

// ---------------- big GEMM: h_pre += c_d * relu(z-grids) @ fs ----------------
// grid: 896 = 16 mtiles (M=128) x 56 chunks (16 (d,i)-slabs each), 256 thr (4 waves)
// XCD swizzle: bx&7 -> chunk group, so a chunk's 16 mtile-blocks share one XCD's L2.
// LDS: A [8 u][2 s][64][16B] = 16KB, B [16 t][2 s][64][16B] = 32KB
__launch_bounds__(256, 2)
__global__ void gemm_kernel(const float* __restrict__ z,
                            const float* __restrict__ grids,
                            const __hip_bfloat16* __restrict__ fs_t,
                            const float* __restrict__ cw,
                            float* __restrict__ h_pre) {
  __shared__ __align__(16) char lds[49152];
  char* ldsA = lds;
  char* ldsB = lds + 16384;

  int bx = blockIdx.x;
  int xcd = bx & 7;
  int j = bx >> 3;                 // [0,112)
  int chunk = xcd * 7 + (j >> 4);  // [0,56)
  int mtile = j & 15;
  int d = chunk >> 3;
  int ibase = (chunk & 7) * 16;

  int tid = threadIdx.x;
  int w = tid >> 6, l = tid & 63;
  int l15 = l & 15, l4 = l >> 4;

  floatx4 acc[8][4];
#pragma unroll
  for (int a = 0; a < 8; ++a)
#pragma unroll
    for (int b = 0; b < 4; ++b) acc[a][b] = (floatx4)0.f;

  int mrow0 = mtile * 128 + 16 * (w * 2 + 0) + l15;
  int mrow1 = mtile * 128 + 16 * (w * 2 + 1) + l15;

  const __hip_bfloat16* fsd = fs_t + (size_t)d * 128 * (HID * GRIDN);

  for (int it = 0; it < 32; ++it) {
    int i = ibase + (it >> 1);
    int kh = it & 1;

    float zv0 = z[(size_t)mrow0 * IN_DIM + i];
    float zv1 = z[(size_t)mrow1 * IN_DIM + i];
    const float* gp = grids + ((size_t)d * IN_DIM + i) * GRIDN + kh * 64 + l4 * 8;
    float4 ga0 = *(const float4*)(gp);
    float4 ga1 = *(const float4*)(gp + 4);
    float4 gb0 = *(const float4*)(gp + 32);
    float4 gb1 = *(const float4*)(gp + 36);

    __syncthreads();  // previous compute done reading LDS

    // async B staging: wave w fills t2 = w*4 .. w*4+3, both ksteps
    const __hip_bfloat16* fsslab = fsd + (size_t)i * (HID * GRIDN);
#pragma unroll
    for (int j2 = 0; j2 < 8; ++j2) {
      int t2 = w * 4 + (j2 >> 1);
      int s2 = j2 & 1;
      const __hip_bfloat16* g =
          fsslab + (size_t)(16 * t2 + l15) * GRIDN + kh * 64 + s2 * 32 + l4 * 8;
      gload_lds16(g, ldsB + (t2 * 2 + s2) * 1024);
    }

    // A generation: relu(z - grid), bf16, fragment-native layout
#pragma unroll
    for (int jj = 0; jj < 2; ++jj) {
      float zv = jj ? zv1 : zv0;
      int u = w * 2 + jj;
#pragma unroll
      for (int s = 0; s < 2; ++s) {
        float4 gA = s ? gb0 : ga0;
        float4 gB = s ? gb1 : ga1;
        float a0 = fmaxf(zv - gA.x, 0.f), a1 = fmaxf(zv - gA.y, 0.f);
        float a2 = fmaxf(zv - gA.z, 0.f), a3 = fmaxf(zv - gA.w, 0.f);
        float a4 = fmaxf(zv - gB.x, 0.f), a5 = fmaxf(zv - gB.y, 0.f);
        float a6 = fmaxf(zv - gB.z, 0.f), a7 = fmaxf(zv - gB.w, 0.f);
        uint4 pk;
        pk.x = pack2_bf16(a0, a1); pk.y = pack2_bf16(a2, a3);
        pk.z = pack2_bf16(a4, a5); pk.w = pack2_bf16(a6, a7);
        *(uint4*)(ldsA + (((u * 2 + s) * 64 + l) * 16)) = pk;
      }
    }
    __syncthreads();  // staging (incl. async loads) visible

    // compute: 2 ksteps x (8 A-frags x 4 B-frags) = 64 MFMAs
#pragma unroll
    for (int s = 0; s < 2; ++s) {
      short8 af[8], bf[4];
#pragma unroll
      for (int uu = 0; uu < 8; ++uu)
        af[uu] = *(const short8*)(ldsA + (((uu * 2 + s) * 64 + l) * 16));
#pragma unroll
      for (int tt = 0; tt < 4; ++tt)
        bf[tt] = *(const short8*)(ldsB + ((((w * 4 + tt) * 2 + s) * 64 + l) * 16));
#pragma unroll
      for (int uu = 0; uu < 8; ++uu)
#pragma unroll
        for (int tt = 0; tt < 4; ++tt)
          acc[uu][tt] = __builtin_amdgcn_mfma_f32_16x16x32_bf16(af[uu], bf[tt], acc[uu][tt], 0, 0, 0);
    }
  }

  // epilogue: scale by c_d, atomic accumulate
  float cd = cw[d];
  int row0 = mtile * 128 + l4 * 4;
  int col0 = w * 64 + l15;
#pragma unroll
  for (int uu = 0; uu < 8; ++uu) {
#pragma unroll
    for (int tt = 0; tt < 4; ++tt) {
      int col = col0 + tt * 16;
#pragma unroll
      for (int r = 0; r < 4; ++r) {
        int row = row0 + uu * 16 + r;
        atomicAdd(&h_pre[(size_t)row * HID + col], cd * acc[uu][tt][r]);
      }
    }
  }
}

// ---------------- MLP layer: Y = act(X) @ W + b, col stats of Y ----------------
template <int FIRST>
__global__ void mlp_kernel(const float* __restrict__ Xin,
                           const float* __restrict__ statsIn,
                           const float* __restrict__ gamma,
                           const float* __restrict__ beta,
                           const float* __restrict__ W,
                           const float* __restrict__ bias,
                           float* __restrict__ Yout,
                           float* __restrict__ statsOut) {
  __shared__ float Xs[4][HID];
  int br = blockIdx.x, c = threadIdx.x;
  float mean = 0.f, rstd = 1.f, gm = 1.f, bt = 0.f;
  if (!FIRST) {
    float s1 = statsIn[c], s2 = statsIn[HID + c];
    mean = s1 * (1.0f / BATCH);
    float var = s2 * (1.0f / BATCH) - mean * mean;
    rstd = rsqrtf(var + 1e-5f);
    gm = gamma[c]; bt = beta[c];
  }
#pragma unroll
  for (int r = 0; r < 4; ++r) {
    float v = Xin[(size_t)(br * 4 + r) * HID + c];
    if (!FIRST) v = gelu_exact((v - mean) * rstd * gm + bt);
    Xs[r][c] = v;
  }
  __syncthreads();
  float acc[4] = {0, 0, 0, 0};
  for (int k = 0; k < HID; ++k) {
    float wv = W[(size_t)k * HID + c];
#pragma unroll
    for (int r = 0; r < 4; ++r) acc[r] += Xs[r][k] * wv;
  }
  float bb = bias[c];
  float s1 = 0.f, s2 = 0.f;
#pragma unroll
  for (int r = 0; r < 4; ++r) {
    float y = acc[r] + bb;
    Yout[(size_t)(br * 4 + r) * HID + c] = y;
    s1 += y; s2 += y * y;
  }
  atomicAdd(&statsOut[c], s1);
  atomicAdd(&statsOut[HID + c], s2);
}

// ---------------- final: out = gelu(bn(Y3)) @ W_out + b_out ----------------
__global__ void final_kernel(const float* __restrict__ Y3,
                             const float* __restrict__ statsIn,
                             const float* __restrict__ gamma,
                             const float* __restrict__ beta,
                             const float* __restrict__ W_out,
                             const float* __restrict__ b_out,
                             float* __restrict__ out) {
  int w = threadIdx.x >> 6, l = threadIdx.x & 63;
  int b = blockIdx.x * 4 + w;
  float4 y = *(const float4*)(Y3 + (size_t)b * HID + l * 4);
  float4 wv = *(const float4*)(W_out + l * 4);
  float r4[4] = {y.x, y.y, y.z, y.w};
  float w4[4] = {wv.x, wv.y, wv.z, wv.w};
  float s = 0.f;
  int c0 = l * 4;
#pragma unroll
  for (int q = 0; q < 4; ++q) {
    int c = c0 + q;
    float s1 = statsIn[c], s2 = statsIn[HID + c];
    float mean = s1 * (1.0f / BATCH);
    float var = s2 * (1.0f / BATCH) - mean * mean;
    float rstd = rsqrtf(var + 1e-5f);
    float v = gelu_exact((r4[q] - mean) * rstd * gamma[c] + beta[c]);
    s += v * w4[q];
  }
#pragma unroll
  for (int off = 32; off > 0; off >>= 1) s += __shfl_down(s, off);
  if (l == 0) out[b] = s + b_out[0];
}

extern "C" void kernel_launch(void* const* d_in, const int* in_sizes, int n_in,
                              void* d_out, int out_size, void* d_ws, size_t ws_size,
                              hipStream_t stream) {
  const float* x      = (const float*)d_in[0];
  const float* grids  = (const float*)d_in[1];
  const float* fs     = (const float*)d_in[2];
  const float* dscore = (const float*)d_in[3];
  const float* mlp_W  = (const float*)d_in[4];
  const float* mlp_b  = (const float*)d_in[5];
  const float* bn_g   = (const float*)d_in[6];
  const float* bn_b   = (const float*)d_in[7];
  const float* W_out  = (const float*)d_in[8];
  const float* b_out  = (const float*)d_in[9];
  float* out = (float*)d_out;

  char* ws = (char*)d_ws;
  __hip_bfloat16* fs_t = (__hip_bfloat16*)(ws + OFF_FST);
  float* z     = (float*)(ws + OFF_Z);
  float* h_pre = (float*)(ws + OFF_HPRE);
  float* stats = (float*)(ws + OFF_STATS);
  u32*   keys  = (u32*)(ws + OFF_KEYS);
  float* cw    = (float*)(ws + OFF_CW);
  float* Y1    = (float*)(ws + OFF_Y1);
  float* Y2    = (float*)(ws + OFF_Y2);
  float* Y3    = (float*)(ws + OFF_Y3);

  // zero the atomic accumulators (h_pre + BN stats + minmax keys)
  hipMemsetAsync(h_pre, 0, SZ_HPRE + SZ_STATS + SZ_KEYS, stream);

  prep1_kernel<<<64, 256, 0, stream>>>(x, keys);
  prep2_kernel<<<256, 256, 0, stream>>>(x, keys, dscore, z, cw);
  convert_kernel<<<DEPTH * IN_DIM, 256, 0, stream>>>(fs, fs_t);
  gemm_kernel<<<896, 256, 0, stream>>>(z, grids, fs_t, cw, h_pre);

  mlp_kernel<1><<<512, 256, 0, stream>>>(h_pre, nullptr, nullptr, nullptr,
                                         mlp_W, mlp_b, Y1, stats);
  mlp_kernel<0><<<512, 256, 0, stream>>>(Y1, stats, bn_g, bn_b,
                                         mlp_W + 65536, mlp_b + 256, Y2, stats + 512);
  mlp_kernel<0><<<512, 256, 0, stream>>>(Y2, stats + 512, bn_g + 256, bn_b + 256,
                                         mlp_W + 2 * 65536, mlp_b + 2 * 256, Y3, stats + 1024);
  final_kernel<<<512, 256, 0, stream>>>(Y3, stats + 1024, bn_g + 512, bn_b + 512,
                                        W_out, b_out, out);
}